// Round 6
// baseline (296.972 us; speedup 1.0000x reference)
//
#include <hip/hip_runtime.h>

typedef _Float16 half8 __attribute__((ext_vector_type(8)));
typedef float f32x16 __attribute__((ext_vector_type(16)));

// Problem constants
#define EDIM 256
#define NE   1024
#define HW   4096

// d_out layout (fp32 elements): z_q[16777216], loss, perplexity, idx[65536]
#define ZQ_OFF   0
#define LOSS_OFF 16777216
#define PERP_OFF 16777217
#define IDX_OFF  16777218

// ws layout (byte offsets)
#define WS_ESPH    0                         // eh fragment-ordered f16, 512 KB
#define WS_BNORM   (1024*1024)               // 1024 f32
#define WS_COUNTS  (WS_BNORM + 4096)         // 1024 i32
#define WS_COUNTER (WS_COUNTS + 4096)        // i32 (+pad)
#define WS_LOSS    (WS_COUNTER + 16)         // double
#define WS_AN      (WS_LOSS + 16)            // 65536 f32
#define WS_IDX     (WS_AN + 65536*4)         // 65536 i32
#define WS_LIST    (WS_IDX + 65536*4)        // 65536 i32
#define WS_ET      (WS_LIST + 65536*4)       // eT[c][j] f32, 1 MB (16B aligned)

// refine margin in d-units; provable distortion bound ~1.9e-4 (single-term
// split residual 9.6e-5 + numpy fp32 rounding 9.2e-5). 1.6x safety.
#define EPS 3.0e-4f
// g = acc - 512*B_j tracked in max-domain; gap test g1-g2 < 512*EPS
#define GEPS (512.0f * EPS)

#define AS1 __attribute__((address_space(1)))
#define AS3 __attribute__((address_space(3)))

// ---------------------------------------------------------------------------
// numpy pairwise_sum replica for a 128-element block of squares.
// ---------------------------------------------------------------------------
__device__ __forceinline__ float np_half128(const float* __restrict__ p, long stride) {
#pragma clang fp contract(off)
    float r[8];
#pragma unroll
    for (int j = 0; j < 8; ++j) { float v = p[(long)j * stride]; r[j] = v * v; }
    for (int i = 8; i < 128; i += 8) {
#pragma unroll
        for (int j = 0; j < 8; ++j) { float v = p[(long)(i + j) * stride]; r[j] += v * v; }
    }
    return ((r[0] + r[1]) + (r[2] + r[3])) + ((r[4] + r[5]) + (r[6] + r[7]));
}

// ---------------------------------------------------------------------------
// K0: e*1024 -> f16 hi, FRAGMENT-ORDERED for 32x32x16 MFMA staging.
// ---------------------------------------------------------------------------
__global__ void k_prep_e(const float* __restrict__ e, _Float16* __restrict__ eh) {
    int t = blockIdx.x * 256 + threadIdx.x;   // 262144
    int j = t >> 8, c = t & 255;
    float v = e[t] * 1024.0f;                 // exact pow2 scale
    _Float16 h = (_Float16)v;
    int jt = j >> 7, nt = (j >> 5) & 3, lm = j & 31;
    int kc = c >> 5, r = c & 31, kh = r >> 4, hb = (r >> 3) & 1, kk = r & 7;
    int chunk = (((jt * 8 + kc) * 4 + nt) * 2 + kh) * 64 + hb * 32 + lm;
    eh[chunk * 8 + kk] = h;
}

// ---------------------------------------------------------------------------
// K0b: raw fp32 transpose e[j][c] -> eT[c][j] via LDS tile (coalesced both
// sides). 32 j-rows per block, 32 blocks.
// ---------------------------------------------------------------------------
__global__ void k_transpose(const float* __restrict__ e, float* __restrict__ eT) {
    __shared__ float tile[32][257];
    int b = blockIdx.x;            // j-tile [32b, 32b+32)
    int t = threadIdx.x;
#pragma unroll
    for (int i = 0; i < 32; ++i)
        tile[i][t] = e[(size_t)(32 * b + i) * 256 + t];
    __syncthreads();
    int jl = t & 31, cg = t >> 5;  // 8 c-groups of 32 lanes
#pragma unroll
    for (int k = 0; k < 32; ++k) {
        int c = cg * 32 + k;
        eT[(size_t)c * 1024 + 32 * b + jl] = tile[jl][c];
    }
}

// ---------------------------------------------------------------------------
// K1: B_j = numpy-pairwise sum of e[j][:]^2
// ---------------------------------------------------------------------------
__global__ void k_bnorm(const float* __restrict__ e, float* __restrict__ Bn) {
    int j = blockIdx.x * 256 + threadIdx.x;   // grid 4
    const float* p = e + (size_t)j * EDIM;
    Bn[j] = np_half128(p, 1) + np_half128(p + 128, 1);
}

// ---------------------------------------------------------------------------
// K2: A_n = numpy-pairwise sum of zf[n][:]^2 ; accumulate Sum(A_n) into loss
// ---------------------------------------------------------------------------
__global__ void k_rownorm(const float* __restrict__ z, float* __restrict__ An,
                          double* __restrict__ loss_sum) {
    __shared__ double ls[4];
    int t = threadIdx.x;
    int n = blockIdx.x * 256 + t;             // grid 256
    int b = n >> 12, hw = n & 4095;
    const float* p = z + (size_t)b * (EDIM * HW) + hw;
    float a = np_half128(p, HW) + np_half128(p + (size_t)128 * HW, HW);
    An[n] = a;
    double s = (double)a;
#pragma unroll
    for (int sh = 1; sh < 64; sh <<= 1) s += __shfl_xor(s, sh, 64);
    if ((t & 63) == 0) ls[t >> 6] = s;
    __syncthreads();
    if (t == 0) atomicAdd(loss_sum, (ls[0] + ls[1]) + (ls[2] + ls[3]));
}

// ---------------------------------------------------------------------------
// K3 v4: single-term f16 MFMA distance + top-2 argmin + loss + histogram.
// 512 blocks x 256 thr (4 waves x 32 rows = 128 rows/block), 2 blocks/CU.
// eh staged in HALF-JT chunks (32 KB) into double-buffered LDS via bulk
// global_load_lds (8x16B/thread). 2 independent blocks per CU: while one
// block sits at its barrier drain / fold, the other feeds the LDS+MFMA
// pipes -- cross-block overlap the 1-block/CU version lacked.
// Bn for jt loaded at jt start (latency hidden under MFMA phase).
// MFMA order per acc: ks=0..15 ascending per jt -> bit-identical to v3.
// ---------------------------------------------------------------------------
__global__ __launch_bounds__(256, 2) void k_dist(
    const float* __restrict__ z, const _Float16* __restrict__ eh,
    const float* __restrict__ Bn, int* __restrict__ idxw,
    float* __restrict__ out, int* __restrict__ counter, int* __restrict__ list,
    double* __restrict__ loss_sum, int* __restrict__ counts)
{
    __shared__ uint4  sB[2][2048];    // 2 x 32 KB (half-jt chunk each)
    __shared__ double lsum[8];
    __shared__ int    lflag[128];
    __shared__ int    lcnt;
    __shared__ int    lbase;

    const int t  = threadIdx.x;       // 0..255
    const int w  = t >> 6;            // 4 waves
    const int L  = t & 63;
    const int l5 = L & 31;
    const int hb = L >> 5;
    const int n0 = blockIdx.x * 128;  // 512 blocks
    const int b  = n0 >> 12, hw0 = n0 & 4095;
    const float* zb = z + (size_t)b * (EDIM * HW) + hw0;
    const int rbase = w * 32;

    if (t == 0) lcnt = 0;

    const uint4* gB4 = (const uint4*)eh;
    const int wb = t & 192;           // w*64: wave-uniform lane-0 slot

    // stage chunk 0 (jt=0, kc 0..3) -- overlaps with the A-fragment build
#pragma unroll
    for (int i = 0; i < 8; ++i)
        __builtin_amdgcn_global_load_lds(
            (const AS1 void*)(gB4 + (i * 256 + t)),
            (AS3 void*)(&sB[0][i * 256 + wb]), 16, 0, 0);

    // A fragments (hi only): lane holds A[m=rbase+l5][k=ks*16+hb*8+j]
    half8 Ah[16];
    {
        int m = rbase + l5;
#pragma unroll
        for (int ks = 0; ks < 16; ++ks) {
            float av[8];
#pragma unroll
            for (int j = 0; j < 8; ++j)
                av[j] = zb[(ks * 16 + hb * 8 + j) * HW + m];
#pragma unroll
            for (int j = 0; j < 8; ++j)
                Ah[ks][j] = (_Float16)av[j];
        }
    }

    f32x16 acc[4];
#pragma unroll
    for (int nt = 0; nt < 4; ++nt)
#pragma unroll
        for (int r = 0; r < 16; ++r) acc[nt][r] = 0.f;

    float g1[16], g2[16]; int i1[16];
#pragma unroll
    for (int r = 0; r < 16; ++r) { g1[r] = -1e30f; g2[r] = -1e30f; i1[r] = 0; }

    float en512[4];

    __syncthreads();   // chunk 0 staged (drain overlapped with Ah build)

    // 16 chunks = 8 jt x 2 halves (h=0: kc 0..3, h=1: kc 4..7)
    for (int ch = 0; ch < 16; ++ch) {
        const int buf = ch & 1;
        const int jt  = ch >> 1, h = ch & 1;

        // issue stage of chunk ch+1 BEFORE compute: latency hides under
        // this chunk's ds_read+MFMA phase.
        if (ch < 15) {
#pragma unroll
            for (int i = 0; i < 8; ++i)
                __builtin_amdgcn_global_load_lds(
                    (const AS1 void*)(gB4 + ((ch + 1) * 2048 + i * 256 + t)),
                    (AS3 void*)(&sB[buf ^ 1][i * 256 + wb]), 16, 0, 0);
        }

        // Bn prefetch at jt start: ~2 chunk-compute phases before use
        if (h == 0) {
#pragma unroll
            for (int nt = 0; nt < 4; ++nt)
                en512[nt] = 512.0f * Bn[jt * 128 + nt * 32 + l5];
        }

        // compute: 32 conflict-free ds_read_b128 + 32 MFMA
#pragma unroll
        for (int kcl = 0; kcl < 4; ++kcl) {
            const int ks0 = h * 8 + kcl * 2;
#pragma unroll
            for (int kh = 0; kh < 2; ++kh) {
#pragma unroll
                for (int nt = 0; nt < 4; ++nt) {
                    half8 bh = *(const half8*)&sB[buf][((kcl * 4 + nt) * 2 + kh) * 64 + L];
                    acc[nt] = __builtin_amdgcn_mfma_f32_32x32x16_f16(
                        Ah[ks0 + kh], bh, acc[nt], 0, 0, 0);
                }
            }
        }

        // end of jt: fold acc -> top2 (max domain), reset acc
        if (h == 1) {
#pragma unroll
            for (int nt = 0; nt < 4; ++nt) {
                int jc = jt * 128 + nt * 32 + l5;
#pragma unroll
                for (int r = 0; r < 16; ++r) {
                    float v = acc[nt][r] - en512[nt];
                    g2[r] = fmaxf(g2[r], fminf(v, g1[r]));   // 2nd-largest
                    bool gt = v > g1[r];                     // strict: first idx wins
                    g1[r] = fmaxf(v, g1[r]);
                    i1[r] = gt ? jc : i1[r];
                    acc[nt][r] = 0.f;
                }
            }
        }

        __syncthreads();   // chunk ch+1 fully staged; all waves done with buf
    }

    // cross-lane top2 merge over 32 lanes sharing rows (same hb)
    double lossP = 0.0;
#pragma unroll
    for (int r = 0; r < 16; ++r) {
        float v1 = g1[r], v2 = g2[r]; int ii = i1[r];
#pragma unroll
        for (int s = 1; s < 32; s <<= 1) {
            float o1 = __shfl_xor(v1, s, 64);
            int   oi = __shfl_xor(ii, s, 64);
            float o2 = __shfl_xor(v2, s, 64);
            float lo = fminf(v1, o1);
            if (o1 > v1 || (o1 == v1 && oi < ii)) { v1 = o1; ii = oi; }
            v2 = fmaxf(fmaxf(v2, o2), lo);
        }
        if (l5 == 0) {
            int rloc = rbase + 4 * hb + (r & 3) + 8 * (r >> 2);
            int n = n0 + rloc;
            idxw[n] = ii;
            out[IDX_OFF + n] = (float)ii;
            atomicAdd(&counts[ii], 1);
            lossP += -(double)v1 * (1.0 / 512.0);   // d_min = -g1/512
            if (v1 - v2 < GEPS) {
                int p = atomicAdd(&lcnt, 1);        // LDS atomic
                if (p < 128) lflag[p] = n;
            }
        }
    }
    if (l5 == 0) lsum[w * 2 + hb] = lossP;
    __syncthreads();
    if (t == 0) {
        atomicAdd(loss_sum, ((lsum[0] + lsum[1]) + (lsum[2] + lsum[3])) +
                            ((lsum[4] + lsum[5]) + (lsum[6] + lsum[7])));
        lbase = lcnt ? atomicAdd(counter, lcnt) : 0;
    }
    __syncthreads();
    for (int i = t; i < lcnt; i += 256) {
        int p = lbase + i;
        if (p < 65536) list[p] = lflag[i];
    }
}

// ---------------------------------------------------------------------------
// K4: numpy-bit-faithful fp32 rescan of flagged rows + histogram delta-fix.
// thread t owns codes 4t..4t+3; e traversed via TRANSPOSED eT[c][j]:
// every wave load is 1KB contiguous. 8 rows/block.
// ---------------------------------------------------------------------------
__global__ __launch_bounds__(256, 2) void k_refine(
    const float* __restrict__ z, const float* __restrict__ eT,
    const float* __restrict__ Bn, const float* __restrict__ An,
    const int* __restrict__ counter, const int* __restrict__ list,
    int* __restrict__ idxw, float* __restrict__ out,
    int* __restrict__ counts)
{
    __shared__ float zs[8][256];
    __shared__ int   ns[8];
    __shared__ float ans[8];
    __shared__ float pv[4][8];
    __shared__ int   pi[4][8];
    int t = threadIdx.x;
    int cnt = min(*counter, 65536);
    for (int li0 = blockIdx.x * 8; li0 < cnt; li0 += gridDim.x * 8) {
        int nrows = min(8, cnt - li0);
        __syncthreads();
        if (t < 8) {
            int n = (t < nrows) ? list[li0 + t] : list[li0];
            ns[t] = n; ans[t] = An[n];
        }
        __syncthreads();
#pragma unroll
        for (int u = 0; u < 8; ++u) {
            int n = ns[u];
            zs[u][t] = z[(size_t)(n >> 12) * (EDIM * HW) + (n & 4095) + t * HW];
        }
        __syncthreads();

        // D[q][r]: dot(e[4t+q], zs[r]) accumulated in c-ascending fmaf order
        float D[4][8];
#pragma unroll
        for (int q = 0; q < 4; ++q)
#pragma unroll
            for (int r = 0; r < 8; ++r) D[q][r] = 0.f;

        for (int c4 = 0; c4 < 64; ++c4) {
            float4 ec[4];                       // codes 4t..4t+3 at c=4*c4+cc
#pragma unroll
            for (int cc = 0; cc < 4; ++cc)
                ec[cc] = *(const float4*)&eT[(size_t)(c4 * 4 + cc) * 1024 + 4 * t];
            float4 zr[8];                       // broadcast ds_read_b128
#pragma unroll
            for (int r = 0; r < 8; ++r)
                zr[r] = *(const float4*)&zs[r][c4 * 4];
#pragma unroll
            for (int cc = 0; cc < 4; ++cc) {
                const float* ep = (const float*)&ec[cc];
#pragma unroll
                for (int r = 0; r < 8; ++r) {
                    float zv = ((const float*)&zr[r])[cc];
                    D[0][r] = __builtin_fmaf(ep[0], zv, D[0][r]);
                    D[1][r] = __builtin_fmaf(ep[1], zv, D[1][r]);
                    D[2][r] = __builtin_fmaf(ep[2], zv, D[2][r]);
                    D[3][r] = __builtin_fmaf(ep[3], zv, D[3][r]);
                }
            }
        }

        float bm[8]; int bi[8];
#pragma unroll
        for (int r = 0; r < 8; ++r) { bm[r] = 1e30f; bi[r] = 1 << 30; }
        float4 bn4 = *(const float4*)&Bn[4 * t];
        {
#pragma clang fp contract(off)
#pragma unroll
            for (int q = 0; q < 4; ++q) {
                float bnj = ((const float*)&bn4)[q];
                int j = 4 * t + q;
#pragma unroll
                for (int r = 0; r < 8; ++r) {
                    float t2 = D[q][r] + D[q][r];
                    float s  = ans[r] + bnj;
                    float d  = s - t2;
                    if (d < bm[r]) { bm[r] = d; bi[r] = j; }   // ascending j: first wins
                }
            }
        }
        int wv = t >> 6, L = t & 63;
#pragma unroll
        for (int r = 0; r < 8; ++r) {
            float v = bm[r]; int ii = bi[r];
#pragma unroll
            for (int s = 1; s < 64; s <<= 1) {
                float ov = __shfl_xor(v, s, 64);
                int   oi = __shfl_xor(ii, s, 64);
                if (ov < v || (ov == v && oi < ii)) { v = ov; ii = oi; }
            }
            if (L == 0) { pv[wv][r] = v; pi[wv][r] = ii; }
        }
        __syncthreads();
        if (t < nrows) {
            float v = pv[0][t]; int ii = pi[0][t];
#pragma unroll
            for (int w2 = 1; w2 < 4; ++w2)
                if (pv[w2][t] < v || (pv[w2][t] == v && pi[w2][t] < ii)) { v = pv[w2][t]; ii = pi[w2][t]; }
            int n = ns[t];
            int old = idxw[n];
            if (old != ii) {
                idxw[n] = ii;
                out[IDX_OFF + n] = (float)ii;
                atomicSub(&counts[old], 1);
                atomicAdd(&counts[ii], 1);
            }
        }
    }
}

// ---------------------------------------------------------------------------
// K5: zq gather/scatter (loss via distance identity; idx final post-refine).
// ---------------------------------------------------------------------------
__global__ void k_gather(const float* __restrict__ e, const int* __restrict__ idxw,
                         float* __restrict__ out) {
    __shared__ int   jrow[256];
    __shared__ float Ls[8][260];
    int t = threadIdx.x;
    int rg = blockIdx.x >> 1, ch = blockIdx.x & 1;
    int n0 = rg * 256;
    int b = n0 >> 12, hw0 = n0 & 4095;
    jrow[t] = idxw[n0 + t];
    float* zqb = out + ZQ_OFF + (size_t)b * (EDIM * HW) + hw0 + (size_t)ch * 128 * HW;
    int w = t >> 6, L = t & 63;
    __syncthreads();

    for (int cc = 0; cc < 16; ++cc) {
        const float4* ep = (const float4*)(e + (size_t)jrow[t] * EDIM + ch * 128 + cc * 8);
        float4 v0 = ep[0], v1 = ep[1];
        Ls[0][t] = v0.x; Ls[1][t] = v0.y; Ls[2][t] = v0.z; Ls[3][t] = v0.w;
        Ls[4][t] = v1.x; Ls[5][t] = v1.y; Ls[6][t] = v1.z; Ls[7][t] = v1.w;
        __syncthreads();
#pragma unroll
        for (int i = 0; i < 2; ++i) {
            int c = w * 2 + i;
            float4 vv = *(const float4*)&Ls[c][L * 4];
            *(float4*)(zqb + (size_t)(cc * 8 + c) * HW + L * 4) = vv;
        }
        __syncthreads();
    }
}

// ---------------------------------------------------------------------------
// K6: finalize scalars
// ---------------------------------------------------------------------------
__global__ void k_final(const int* __restrict__ counts, const double* __restrict__ loss_sum,
                        float* __restrict__ out) {
    __shared__ float sred[4];
    int t = threadIdx.x;
    float s = 0.f;
    for (int qq = 0; qq < 4; ++qq) {
        float p = (float)counts[qq * 256 + t] * (1.0f / 65536.0f);
        s += p * logf(p + 1e-10f);
    }
#pragma unroll
    for (int sh = 1; sh < 64; sh <<= 1) s += __shfl_xor(s, sh, 64);
    if ((t & 63) == 0) sred[t >> 6] = s;
    __syncthreads();
    if (t == 0) {
        out[PERP_OFF] = expf(-(sred[0] + sred[1] + sred[2] + sred[3]));
        out[LOSS_OFF] = (float)(*loss_sum * 1.25 / 16777216.0);
    }
}

extern "C" void kernel_launch(void* const* d_in, const int* in_sizes, int n_in,
                              void* d_out, int out_size, void* d_ws, size_t ws_size,
                              hipStream_t stream) {
    const float* z = (const float*)d_in[0];
    const float* e = (const float*)d_in[1];
    float* out = (float*)d_out;
    char* ws = (char*)d_ws;

    _Float16* eh      = (_Float16*)(ws + WS_ESPH);
    float*    Bn      = (float*)(ws + WS_BNORM);
    int*      counts  = (int*)(ws + WS_COUNTS);
    int*      counter = (int*)(ws + WS_COUNTER);
    double*   loss_sum= (double*)(ws + WS_LOSS);
    float*    An      = (float*)(ws + WS_AN);
    int*      idxw    = (int*)(ws + WS_IDX);
    int*      list    = (int*)(ws + WS_LIST);
    float*    eT      = (float*)(ws + WS_ET);

    // zero counts + counter + loss accumulator (contiguous)
    hipMemsetAsync(ws + WS_COUNTS, 0, 4096 + 16 + 16, stream);

    k_prep_e   <<<1024, 256, 0, stream>>>(e, eh);
    k_transpose<<<32,   256, 0, stream>>>(e, eT);
    k_bnorm    <<<4,    256, 0, stream>>>(e, Bn);
    k_rownorm  <<<256,  256, 0, stream>>>(z, An, loss_sum);
    k_dist     <<<512,  256, 0, stream>>>(z, eh, Bn, idxw, out, counter, list, loss_sum, counts);
    k_refine   <<<2048, 256, 0, stream>>>(z, eT, Bn, An, counter, list, idxw, out, counts);
    k_gather   <<<512,  256, 0, stream>>>(e, idxw, out);
    k_final    <<<1,    256, 0, stream>>>(counts, loss_sum, out);
}

// Round 7
// 262.540 us; speedup vs baseline: 1.1312x; 1.1312x over previous
//
#include <hip/hip_runtime.h>

typedef _Float16 half8 __attribute__((ext_vector_type(8)));
typedef float f32x16 __attribute__((ext_vector_type(16)));

// Problem constants
#define EDIM 256
#define NE   1024
#define HW   4096

// d_out layout (fp32 elements): z_q[16777216], loss, perplexity, idx[65536]
#define ZQ_OFF   0
#define LOSS_OFF 16777216
#define PERP_OFF 16777217
#define IDX_OFF  16777218

// ws layout (byte offsets)
#define WS_ESPH    0                         // eh fragment-ordered f16, 512 KB
#define WS_BNORM   (1024*1024)               // 1024 f32
#define WS_COUNTS  (WS_BNORM + 4096)         // 1024 i32
#define WS_COUNTER (WS_COUNTS + 4096)        // i32 (+pad)
#define WS_LOSS    (WS_COUNTER + 16)         // double
#define WS_AN      (WS_LOSS + 16)            // 65536 f32
#define WS_IDX     (WS_AN + 65536*4)         // 65536 i32
#define WS_LIST    (WS_IDX + 65536*4)        // 65536 i32
#define WS_ET      (WS_LIST + 65536*4)       // eT[c][j] f32, 1 MB (16B aligned)

// refine margin in d-units; provable distortion bound ~1.9e-4 (single-term
// split residual 9.6e-5 + numpy fp32 rounding 9.2e-5). 1.6x safety.
#define EPS 3.0e-4f
// g = acc - 512*B_j tracked in max-domain; gap test g1-g2 < 512*EPS
#define GEPS (512.0f * EPS)

#define AS1 __attribute__((address_space(1)))
#define AS3 __attribute__((address_space(3)))

// ---------------------------------------------------------------------------
// numpy pairwise_sum replica for a 128-element block of squares.
// ---------------------------------------------------------------------------
__device__ __forceinline__ float np_half128(const float* __restrict__ p, long stride) {
#pragma clang fp contract(off)
    float r[8];
#pragma unroll
    for (int j = 0; j < 8; ++j) { float v = p[(long)j * stride]; r[j] = v * v; }
    for (int i = 8; i < 128; i += 8) {
#pragma unroll
        for (int j = 0; j < 8; ++j) { float v = p[(long)(i + j) * stride]; r[j] += v * v; }
    }
    return ((r[0] + r[1]) + (r[2] + r[3])) + ((r[4] + r[5]) + (r[6] + r[7]));
}

// ---------------------------------------------------------------------------
// K0: e*1024 -> f16 hi, FRAGMENT-ORDERED for 32x32x16 MFMA staging.
// ---------------------------------------------------------------------------
__global__ void k_prep_e(const float* __restrict__ e, _Float16* __restrict__ eh) {
    int t = blockIdx.x * 256 + threadIdx.x;   // 262144
    int j = t >> 8, c = t & 255;
    float v = e[t] * 1024.0f;                 // exact pow2 scale
    _Float16 h = (_Float16)v;
    int jt = j >> 7, nt = (j >> 5) & 3, lm = j & 31;
    int kc = c >> 5, r = c & 31, kh = r >> 4, hb = (r >> 3) & 1, kk = r & 7;
    int chunk = (((jt * 8 + kc) * 4 + nt) * 2 + kh) * 64 + hb * 32 + lm;
    eh[chunk * 8 + kk] = h;
}

// ---------------------------------------------------------------------------
// K0b: raw fp32 transpose e[j][c] -> eT[c][j] via LDS tile (coalesced both
// sides). 32 j-rows per block, 32 blocks.
// ---------------------------------------------------------------------------
__global__ void k_transpose(const float* __restrict__ e, float* __restrict__ eT) {
    __shared__ float tile[32][257];
    int b = blockIdx.x;            // j-tile [32b, 32b+32)
    int t = threadIdx.x;
#pragma unroll
    for (int i = 0; i < 32; ++i)
        tile[i][t] = e[(size_t)(32 * b + i) * 256 + t];
    __syncthreads();
    int jl = t & 31, cg = t >> 5;  // 8 c-groups of 32 lanes
#pragma unroll
    for (int k = 0; k < 32; ++k) {
        int c = cg * 32 + k;
        eT[(size_t)c * 1024 + 32 * b + jl] = tile[jl][c];
    }
}

// ---------------------------------------------------------------------------
// K1: B_j = numpy-pairwise sum of e[j][:]^2
// ---------------------------------------------------------------------------
__global__ void k_bnorm(const float* __restrict__ e, float* __restrict__ Bn) {
    int j = blockIdx.x * 256 + threadIdx.x;   // grid 4
    const float* p = e + (size_t)j * EDIM;
    Bn[j] = np_half128(p, 1) + np_half128(p + 128, 1);
}

// ---------------------------------------------------------------------------
// K2: A_n = numpy-pairwise sum of zf[n][:]^2 ; accumulate Sum(A_n) into loss
// ---------------------------------------------------------------------------
__global__ void k_rownorm(const float* __restrict__ z, float* __restrict__ An,
                          double* __restrict__ loss_sum) {
    __shared__ double ls[4];
    int t = threadIdx.x;
    int n = blockIdx.x * 256 + t;             // grid 256
    int b = n >> 12, hw = n & 4095;
    const float* p = z + (size_t)b * (EDIM * HW) + hw;
    float a = np_half128(p, HW) + np_half128(p + (size_t)128 * HW, HW);
    An[n] = a;
    double s = (double)a;
#pragma unroll
    for (int sh = 1; sh < 64; sh <<= 1) s += __shfl_xor(s, sh, 64);
    if ((t & 63) == 0) ls[t >> 6] = s;
    __syncthreads();
    if (t == 0) atomicAdd(loss_sum, (ls[0] + ls[1]) + (ls[2] + ls[3]));
}

// ---------------------------------------------------------------------------
// K3 v5: single-term f16 MFMA distance + top-2 argmin + loss + histogram.
// 256 blocks x 512 thr (8 waves x 32 rows), 1 block/CU -- the v3 shape.
// T3/T4 counted-vmcnt pipeline: 16 half-jt chunks (32 KB), 4 LDS buffers,
// 3-deep prefetch via global_load_lds; raw s_barrier + s_waitcnt vmcnt(8)
// (never 0 in steady state) so 8 staging loads stay in flight across every
// barrier -- no per-chunk full drain. Bn copied to LDS so the loop's vmcnt
// stream contains ONLY staging loads (exact in-order accounting).
// MFMA order (kc asc, kh, nt) identical to v3 -> bit-identical results.
// ---------------------------------------------------------------------------
#define WAITV(n) asm volatile("s_waitcnt vmcnt(" #n ") lgkmcnt(0)" ::: "memory")
#define FENCE()  asm volatile("" ::: "memory")
#define BARRIER() __builtin_amdgcn_s_barrier()

#define STAGE(S) do {                                                          \
    _Pragma("unroll")                                                          \
    for (int i_ = 0; i_ < 4; ++i_)                                             \
        __builtin_amdgcn_global_load_lds(                                      \
            (const AS1 void*)(gB4 + ((S) * 2048 + i_ * 512 + t)),              \
            (AS3 void*)(&sB[(S) & 3][i_ * 512 + wb]), 16, 0, 0);               \
} while (0)

#define CHALF(BUF, H) do {                                                     \
    _Pragma("unroll")                                                          \
    for (int kcl = 0; kcl < 4; ++kcl) {                                        \
        _Pragma("unroll")                                                      \
        for (int kh = 0; kh < 2; ++kh) {                                       \
            _Pragma("unroll")                                                  \
            for (int nt = 0; nt < 4; ++nt) {                                   \
                half8 bh = *(const half8*)&sB[BUF][((kcl * 4 + nt) * 2 + kh) * 64 + L]; \
                acc[nt] = __builtin_amdgcn_mfma_f32_32x32x16_f16(              \
                    Ah[(H) * 8 + kcl * 2 + kh], bh, acc[nt], 0, 0, 0);         \
            }                                                                  \
        }                                                                      \
    }                                                                          \
} while (0)

#define FOLD(JT) do {                                                          \
    _Pragma("unroll")                                                          \
    for (int nt = 0; nt < 4; ++nt) {                                           \
        float en = 512.0f * bnS[(JT) * 128 + nt * 32 + l5];                    \
        int jc = (JT) * 128 + nt * 32 + l5;                                    \
        _Pragma("unroll")                                                      \
        for (int r = 0; r < 16; ++r) {                                         \
            float v = acc[nt][r] - en;                                         \
            g2[r] = fmaxf(g2[r], fminf(v, g1[r]));                             \
            bool gt = v > g1[r];                                               \
            g1[r] = fmaxf(v, g1[r]);                                           \
            i1[r] = gt ? jc : i1[r];                                           \
            acc[nt][r] = 0.f;                                                  \
        }                                                                      \
    }                                                                          \
} while (0)

__global__ __launch_bounds__(512, 2) void k_dist(
    const float* __restrict__ z, const _Float16* __restrict__ eh,
    const float* __restrict__ Bn, int* __restrict__ idxw,
    float* __restrict__ out, int* __restrict__ counter, int* __restrict__ list,
    double* __restrict__ loss_sum, int* __restrict__ counts)
{
    __shared__ uint4  sB[4][2048];    // 4 x 32 KB ring (half-jt chunks)
    __shared__ float  bnS[1024];      // Bn copy (keeps loop vmcnt clean)
    __shared__ double lsum[16];
    __shared__ int    lflag[256];
    __shared__ int    lcnt;
    __shared__ int    lbase;

    const int t  = threadIdx.x;       // 0..511
    const int w  = t >> 6;            // 8 waves
    const int L  = t & 63;
    const int l5 = L & 31;
    const int hb = L >> 5;
    const int n0 = blockIdx.x * 256;  // 256 blocks
    const int b  = n0 >> 12, hw0 = n0 & 4095;
    const float* zb = z + (size_t)b * (EDIM * HW) + hw0;
    const int rbase = w * 32;

    if (t == 0) lcnt = 0;
    // Bn -> LDS (retired via compiler's value-waits before the loop)
    bnS[t]       = Bn[t];
    bnS[t + 512] = Bn[t + 512];

    const uint4* gB4 = (const uint4*)eh;
    const int wb = t & 448;           // w*64: wave-uniform lane-0 slot

    // prologue: 3-deep prefetch (12 VMEM insts/wave outstanding)
    STAGE(0); STAGE(1); STAGE(2);

    // A fragments (hi only): lane holds A[m=rbase+l5][k=ks*16+hb*8+j]
    half8 Ah[16];
    {
        int m = rbase + l5;
#pragma unroll
        for (int ks = 0; ks < 16; ++ks) {
            float av[8];
#pragma unroll
            for (int j = 0; j < 8; ++j)
                av[j] = zb[(ks * 16 + hb * 8 + j) * HW + m];
#pragma unroll
            for (int j = 0; j < 8; ++j)
                Ah[ks][j] = (_Float16)av[j];
        }
    }

    f32x16 acc[4];
#pragma unroll
    for (int nt = 0; nt < 4; ++nt)
#pragma unroll
        for (int r = 0; r < 16; ++r) acc[nt][r] = 0.f;

    float g1[16], g2[16]; int i1[16];
#pragma unroll
    for (int r = 0; r < 16; ++r) { g1[r] = -1e30f; g2[r] = -1e30f; i1[r] = 0; }

    // main pipeline: chunk c computed after vmcnt confirms its 4 oldest
    // staging loads retired; stage(c+3) issued AFTER barrier(c) so the
    // reused ring slot (c-1)&3 is safe (all waves finished reading it).
    for (int jt = 0; jt < 6; ++jt) {
        WAITV(8); BARRIER(); FENCE();          // c = 2jt ready
        STAGE(2 * jt + 3);
        CHALF((2 * jt) & 3, 0);
        WAITV(8); BARRIER(); FENCE();          // c = 2jt+1 ready
        STAGE(2 * jt + 4);
        CHALF((2 * jt + 1) & 3, 1);
        FOLD(jt);
    }
    // jt = 6 (c = 12, 13): last stage issued at c=12
    WAITV(8); BARRIER(); FENCE();
    STAGE(15);
    CHALF(0, 0);
    WAITV(8); BARRIER(); FENCE();
    CHALF(1, 1);
    FOLD(6);
    // jt = 7 (c = 14, 15): drain tail 8 -> 4 -> 0
    WAITV(4); BARRIER(); FENCE();
    CHALF(2, 0);
    WAITV(0); BARRIER(); FENCE();
    CHALF(3, 1);
    FOLD(7);

    // cross-lane top2 merge over 32 lanes sharing rows (same hb)
    double lossP = 0.0;
#pragma unroll
    for (int r = 0; r < 16; ++r) {
        float v1 = g1[r], v2 = g2[r]; int ii = i1[r];
#pragma unroll
        for (int s = 1; s < 32; s <<= 1) {
            float o1 = __shfl_xor(v1, s, 64);
            int   oi = __shfl_xor(ii, s, 64);
            float o2 = __shfl_xor(v2, s, 64);
            float lo = fminf(v1, o1);
            if (o1 > v1 || (o1 == v1 && oi < ii)) { v1 = o1; ii = oi; }
            v2 = fmaxf(fmaxf(v2, o2), lo);
        }
        if (l5 == 0) {
            int rloc = rbase + 4 * hb + (r & 3) + 8 * (r >> 2);
            int n = n0 + rloc;
            idxw[n] = ii;
            out[IDX_OFF + n] = (float)ii;
            atomicAdd(&counts[ii], 1);
            lossP += -(double)v1 * (1.0 / 512.0);   // d_min = -g1/512
            if (v1 - v2 < GEPS) {
                int p = atomicAdd(&lcnt, 1);        // LDS atomic
                if (p < 256) lflag[p] = n;
            }
        }
    }
    if (l5 == 0) lsum[w * 2 + hb] = lossP;
    __syncthreads();
    if (t == 0) {
        double s = 0.0;
#pragma unroll
        for (int i = 0; i < 16; ++i) s += lsum[i];
        atomicAdd(loss_sum, s);
        lbase = lcnt ? atomicAdd(counter, lcnt) : 0;
    }
    __syncthreads();
    for (int i = t; i < lcnt; i += 512) {
        int p = lbase + i;
        if (p < 65536) list[p] = lflag[i];
    }
}

// ---------------------------------------------------------------------------
// K4: numpy-bit-faithful fp32 rescan of flagged rows + histogram delta-fix.
// thread t owns codes 4t..4t+3; e traversed via TRANSPOSED eT[c][j]:
// every wave load is 1KB contiguous. 8 rows/block.
// ---------------------------------------------------------------------------
__global__ __launch_bounds__(256, 2) void k_refine(
    const float* __restrict__ z, const float* __restrict__ eT,
    const float* __restrict__ Bn, const float* __restrict__ An,
    const int* __restrict__ counter, const int* __restrict__ list,
    int* __restrict__ idxw, float* __restrict__ out,
    int* __restrict__ counts)
{
    __shared__ float zs[8][256];
    __shared__ int   ns[8];
    __shared__ float ans[8];
    __shared__ float pv[4][8];
    __shared__ int   pi[4][8];
    int t = threadIdx.x;
    int cnt = min(*counter, 65536);
    for (int li0 = blockIdx.x * 8; li0 < cnt; li0 += gridDim.x * 8) {
        int nrows = min(8, cnt - li0);
        __syncthreads();
        if (t < 8) {
            int n = (t < nrows) ? list[li0 + t] : list[li0];
            ns[t] = n; ans[t] = An[n];
        }
        __syncthreads();
#pragma unroll
        for (int u = 0; u < 8; ++u) {
            int n = ns[u];
            zs[u][t] = z[(size_t)(n >> 12) * (EDIM * HW) + (n & 4095) + t * HW];
        }
        __syncthreads();

        // D[q][r]: dot(e[4t+q], zs[r]) accumulated in c-ascending fmaf order
        float D[4][8];
#pragma unroll
        for (int q = 0; q < 4; ++q)
#pragma unroll
            for (int r = 0; r < 8; ++r) D[q][r] = 0.f;

        for (int c4 = 0; c4 < 64; ++c4) {
            float4 ec[4];                       // codes 4t..4t+3 at c=4*c4+cc
#pragma unroll
            for (int cc = 0; cc < 4; ++cc)
                ec[cc] = *(const float4*)&eT[(size_t)(c4 * 4 + cc) * 1024 + 4 * t];
            float4 zr[8];                       // broadcast ds_read_b128
#pragma unroll
            for (int r = 0; r < 8; ++r)
                zr[r] = *(const float4*)&zs[r][c4 * 4];
#pragma unroll
            for (int cc = 0; cc < 4; ++cc) {
                const float* ep = (const float*)&ec[cc];
#pragma unroll
                for (int r = 0; r < 8; ++r) {
                    float zv = ((const float*)&zr[r])[cc];
                    D[0][r] = __builtin_fmaf(ep[0], zv, D[0][r]);
                    D[1][r] = __builtin_fmaf(ep[1], zv, D[1][r]);
                    D[2][r] = __builtin_fmaf(ep[2], zv, D[2][r]);
                    D[3][r] = __builtin_fmaf(ep[3], zv, D[3][r]);
                }
            }
        }

        float bm[8]; int bi[8];
#pragma unroll
        for (int r = 0; r < 8; ++r) { bm[r] = 1e30f; bi[r] = 1 << 30; }
        float4 bn4 = *(const float4*)&Bn[4 * t];
        {
#pragma clang fp contract(off)
#pragma unroll
            for (int q = 0; q < 4; ++q) {
                float bnj = ((const float*)&bn4)[q];
                int j = 4 * t + q;
#pragma unroll
                for (int r = 0; r < 8; ++r) {
                    float t2 = D[q][r] + D[q][r];
                    float s  = ans[r] + bnj;
                    float d  = s - t2;
                    if (d < bm[r]) { bm[r] = d; bi[r] = j; }   // ascending j: first wins
                }
            }
        }
        int wv = t >> 6, L = t & 63;
#pragma unroll
        for (int r = 0; r < 8; ++r) {
            float v = bm[r]; int ii = bi[r];
#pragma unroll
            for (int s = 1; s < 64; s <<= 1) {
                float ov = __shfl_xor(v, s, 64);
                int   oi = __shfl_xor(ii, s, 64);
                if (ov < v || (ov == v && oi < ii)) { v = ov; ii = oi; }
            }
            if (L == 0) { pv[wv][r] = v; pi[wv][r] = ii; }
        }
        __syncthreads();
        if (t < nrows) {
            float v = pv[0][t]; int ii = pi[0][t];
#pragma unroll
            for (int w2 = 1; w2 < 4; ++w2)
                if (pv[w2][t] < v || (pv[w2][t] == v && pi[w2][t] < ii)) { v = pv[w2][t]; ii = pi[w2][t]; }
            int n = ns[t];
            int old = idxw[n];
            if (old != ii) {
                idxw[n] = ii;
                out[IDX_OFF + n] = (float)ii;
                atomicSub(&counts[old], 1);
                atomicAdd(&counts[ii], 1);
            }
        }
    }
}

// ---------------------------------------------------------------------------
// K5: zq gather/scatter (loss via distance identity; idx final post-refine).
// ---------------------------------------------------------------------------
__global__ void k_gather(const float* __restrict__ e, const int* __restrict__ idxw,
                         float* __restrict__ out) {
    __shared__ int   jrow[256];
    __shared__ float Ls[8][260];
    int t = threadIdx.x;
    int rg = blockIdx.x >> 1, ch = blockIdx.x & 1;
    int n0 = rg * 256;
    int b = n0 >> 12, hw0 = n0 & 4095;
    jrow[t] = idxw[n0 + t];
    float* zqb = out + ZQ_OFF + (size_t)b * (EDIM * HW) + hw0 + (size_t)ch * 128 * HW;
    int w = t >> 6, L = t & 63;
    __syncthreads();

    for (int cc = 0; cc < 16; ++cc) {
        const float4* ep = (const float4*)(e + (size_t)jrow[t] * EDIM + ch * 128 + cc * 8);
        float4 v0 = ep[0], v1 = ep[1];
        Ls[0][t] = v0.x; Ls[1][t] = v0.y; Ls[2][t] = v0.z; Ls[3][t] = v0.w;
        Ls[4][t] = v1.x; Ls[5][t] = v1.y; Ls[6][t] = v1.z; Ls[7][t] = v1.w;
        __syncthreads();
#pragma unroll
        for (int i = 0; i < 2; ++i) {
            int c = w * 2 + i;
            float4 vv = *(const float4*)&Ls[c][L * 4];
            *(float4*)(zqb + (size_t)(cc * 8 + c) * HW + L * 4) = vv;
        }
        __syncthreads();
    }
}

// ---------------------------------------------------------------------------
// K6: finalize scalars
// ---------------------------------------------------------------------------
__global__ void k_final(const int* __restrict__ counts, const double* __restrict__ loss_sum,
                        float* __restrict__ out) {
    __shared__ float sred[4];
    int t = threadIdx.x;
    float s = 0.f;
    for (int qq = 0; qq < 4; ++qq) {
        float p = (float)counts[qq * 256 + t] * (1.0f / 65536.0f);
        s += p * logf(p + 1e-10f);
    }
#pragma unroll
    for (int sh = 1; sh < 64; sh <<= 1) s += __shfl_xor(s, sh, 64);
    if ((t & 63) == 0) sred[t >> 6] = s;
    __syncthreads();
    if (t == 0) {
        out[PERP_OFF] = expf(-(sred[0] + sred[1] + sred[2] + sred[3]));
        out[LOSS_OFF] = (float)(*loss_sum * 1.25 / 16777216.0);
    }
}

extern "C" void kernel_launch(void* const* d_in, const int* in_sizes, int n_in,
                              void* d_out, int out_size, void* d_ws, size_t ws_size,
                              hipStream_t stream) {
    const float* z = (const float*)d_in[0];
    const float* e = (const float*)d_in[1];
    float* out = (float*)d_out;
    char* ws = (char*)d_ws;

    _Float16* eh      = (_Float16*)(ws + WS_ESPH);
    float*    Bn      = (float*)(ws + WS_BNORM);
    int*      counts  = (int*)(ws + WS_COUNTS);
    int*      counter = (int*)(ws + WS_COUNTER);
    double*   loss_sum= (double*)(ws + WS_LOSS);
    float*    An      = (float*)(ws + WS_AN);
    int*      idxw    = (int*)(ws + WS_IDX);
    int*      list    = (int*)(ws + WS_LIST);
    float*    eT      = (float*)(ws + WS_ET);

    // zero counts + counter + loss accumulator (contiguous)
    hipMemsetAsync(ws + WS_COUNTS, 0, 4096 + 16 + 16, stream);

    k_prep_e   <<<1024, 256, 0, stream>>>(e, eh);
    k_transpose<<<32,   256, 0, stream>>>(e, eT);
    k_bnorm    <<<4,    256, 0, stream>>>(e, Bn);
    k_rownorm  <<<256,  256, 0, stream>>>(z, An, loss_sum);
    k_dist     <<<256,  512, 0, stream>>>(z, eh, Bn, idxw, out, counter, list, loss_sum, counts);
    k_refine   <<<2048, 256, 0, stream>>>(z, eT, Bn, An, counter, list, idxw, out, counts);
    k_gather   <<<512,  256, 0, stream>>>(e, idxw, out);
    k_final    <<<1,    256, 0, stream>>>(counts, loss_sum, out);
}

// Round 8
// 238.993 us; speedup vs baseline: 1.2426x; 1.0985x over previous
//
#include <hip/hip_runtime.h>

typedef _Float16 half8 __attribute__((ext_vector_type(8)));
typedef float f32x16 __attribute__((ext_vector_type(16)));

// Problem constants
#define EDIM 256
#define NE   1024
#define HW   4096

// d_out layout (fp32 elements): z_q[16777216], loss, perplexity, idx[65536]
#define ZQ_OFF   0
#define LOSS_OFF 16777216
#define PERP_OFF 16777217
#define IDX_OFF  16777218

// ws layout (byte offsets)
#define WS_ESPH    0                         // eh fragment-ordered f16, 512 KB
#define WS_BNORM   (1024*1024)               // 1024 f32
#define WS_COUNTS  (WS_BNORM + 4096)         // 1024 i32
#define WS_COUNTER (WS_COUNTS + 4096)        // i32 (+pad)
#define WS_LOSS    (WS_COUNTER + 16)         // double
#define WS_AN      (WS_LOSS + 16)            // 65536 f32
#define WS_IDX     (WS_AN + 65536*4)         // 65536 i32
#define WS_LIST    (WS_IDX + 65536*4)        // 65536 i32
#define WS_ET      (WS_LIST + 65536*4)       // eT[c][j] f32, 1 MB (16B aligned)

// refine margin in d-units; provable distortion bound ~1.9e-4 (single-term
// split residual 9.6e-5 + numpy fp32 rounding 9.2e-5). 1.6x safety.
#define EPS 3.0e-4f
// g = acc - 512*B_j tracked in max-domain; gap test g1-g2 < 512*EPS
#define GEPS (512.0f * EPS)

#define AS1 __attribute__((address_space(1)))
#define AS3 __attribute__((address_space(3)))

// ---------------------------------------------------------------------------
// numpy pairwise_sum replica for a 128-element block of squares.
// ---------------------------------------------------------------------------
__device__ __forceinline__ float np_half128(const float* __restrict__ p, long stride) {
#pragma clang fp contract(off)
    float r[8];
#pragma unroll
    for (int j = 0; j < 8; ++j) { float v = p[(long)j * stride]; r[j] = v * v; }
    for (int i = 8; i < 128; i += 8) {
#pragma unroll
        for (int j = 0; j < 8; ++j) { float v = p[(long)(i + j) * stride]; r[j] += v * v; }
    }
    return ((r[0] + r[1]) + (r[2] + r[3])) + ((r[4] + r[5]) + (r[6] + r[7]));
}

// ---------------------------------------------------------------------------
// K0: e*1024 -> f16 hi, FRAGMENT-ORDERED for 32x32x16 MFMA staging.
// ---------------------------------------------------------------------------
__global__ void k_prep_e(const float* __restrict__ e, _Float16* __restrict__ eh) {
    int t = blockIdx.x * 256 + threadIdx.x;   // 262144
    int j = t >> 8, c = t & 255;
    float v = e[t] * 1024.0f;                 // exact pow2 scale
    _Float16 h = (_Float16)v;
    int jt = j >> 7, nt = (j >> 5) & 3, lm = j & 31;
    int kc = c >> 5, r = c & 31, kh = r >> 4, hb = (r >> 3) & 1, kk = r & 7;
    int chunk = (((jt * 8 + kc) * 4 + nt) * 2 + kh) * 64 + hb * 32 + lm;
    eh[chunk * 8 + kk] = h;
}

// ---------------------------------------------------------------------------
// K0b: raw fp32 transpose e[j][c] -> eT[c][j] via LDS tile (coalesced both
// sides). 32 j-rows per block, 32 blocks.
// ---------------------------------------------------------------------------
__global__ void k_transpose(const float* __restrict__ e, float* __restrict__ eT) {
    __shared__ float tile[32][257];
    int b = blockIdx.x;            // j-tile [32b, 32b+32)
    int t = threadIdx.x;
#pragma unroll
    for (int i = 0; i < 32; ++i)
        tile[i][t] = e[(size_t)(32 * b + i) * 256 + t];
    __syncthreads();
    int jl = t & 31, cg = t >> 5;  // 8 c-groups of 32 lanes
#pragma unroll
    for (int k = 0; k < 32; ++k) {
        int c = cg * 32 + k;
        eT[(size_t)c * 1024 + 32 * b + jl] = tile[jl][c];
    }
}

// ---------------------------------------------------------------------------
// K1: B_j = numpy-pairwise sum of e[j][:]^2
// ---------------------------------------------------------------------------
__global__ void k_bnorm(const float* __restrict__ e, float* __restrict__ Bn) {
    int j = blockIdx.x * 256 + threadIdx.x;   // grid 4
    const float* p = e + (size_t)j * EDIM;
    Bn[j] = np_half128(p, 1) + np_half128(p + 128, 1);
}

// ---------------------------------------------------------------------------
// K3 v6: MFMA distance + top-2 argmin + loss + histogram + FUSED rownorm.
// 256 blocks x 512 thr (8 waves x 32 rows), v3 staging shape (2 x 64 KB
// LDS double-buffer, bulk global_load_lds, one __syncthreads per jt).
// Fused A_n: lane (l5,hb) and partner (l5,hb^1)=L^32 hold complementary
// c-halves of row m. Per ks, 8 shfl_xor(av,32) lets both lanes replay
// numpy's exact alternating-hb pairwise chain (contract-off, reinit at
// ks=8, pairwise combine) -> An bit-identical to the old k_rownorm; the
// 64 MB second read of z is eliminated.
// MFMA order identical to v3 -> bit-identical distances.
// ---------------------------------------------------------------------------
__global__ __launch_bounds__(512, 2) void k_dist(
    const float* __restrict__ z, const _Float16* __restrict__ eh,
    const float* __restrict__ Bn, int* __restrict__ idxw,
    float* __restrict__ out, int* __restrict__ counter, int* __restrict__ list,
    double* __restrict__ loss_sum, int* __restrict__ counts,
    float* __restrict__ An)
{
    __shared__ uint4  sB[2][4096];    // 2 x 64 KB (one jt-chunk each)
    __shared__ double lsum[16];
    __shared__ int    lflag[256];
    __shared__ int    lcnt;
    __shared__ int    lbase;

    const int t  = threadIdx.x;       // 0..511
    const int w  = t >> 6;            // 8 waves
    const int L  = t & 63;
    const int l5 = L & 31;
    const int hb = L >> 5;
    const int n0 = blockIdx.x * 256;  // 256 blocks
    const int b  = n0 >> 12, hw0 = n0 & 4095;
    const float* zb = z + (size_t)b * (EDIM * HW) + hw0;
    const int rbase = w * 32;

    if (t == 0) lcnt = 0;

    const uint4* gB4 = (const uint4*)eh;
    const int wb = t & 448;           // w*64: wave-uniform lane-0 slot

    // stage(jt=0) into buf0 -- overlaps with the preamble below
#pragma unroll
    for (int i = 0; i < 8; ++i)
        __builtin_amdgcn_global_load_lds(
            (const AS1 void*)(gB4 + (i * 512 + t)),
            (AS3 void*)(&sB[0][i * 512 + wb]), 16, 0, 0);

    // Preamble: A fragments + FUSED numpy-exact rownorm.
    // lane holds A[m=rbase+l5][k=ks*16+hb*8+j]; partner L^32 has other half.
    half8 Ah[16];
    double aSred;
    {
        int m = rbase + l5;
        float r[8]; float A1 = 0.f, Aval;
#pragma unroll
        for (int ks = 0; ks < 16; ++ks) {
            float av[8], pv[8];
#pragma unroll
            for (int j = 0; j < 8; ++j)
                av[j] = zb[(ks * 16 + hb * 8 + j) * HW + m];
#pragma unroll
            for (int j = 0; j < 8; ++j)
                pv[j] = __shfl_xor(av[j], 32, 64);
            {
#pragma clang fp contract(off)
#pragma unroll
                for (int j = 0; j < 8; ++j) {
                    float a0 = hb ? pv[j] : av[j];   // first in c-order
                    float a1 = hb ? av[j] : pv[j];   // second in c-order
                    if ((ks & 7) == 0) r[j] = a0 * a0;
                    else               r[j] += a0 * a0;
                    r[j] += a1 * a1;
                }
            }
#pragma unroll
            for (int j = 0; j < 8; ++j)
                Ah[ks][j] = (_Float16)av[j];
            if (ks == 7) {
#pragma clang fp contract(off)
                A1 = ((r[0] + r[1]) + (r[2] + r[3])) + ((r[4] + r[5]) + (r[6] + r[7]));
            }
        }
        {
#pragma clang fp contract(off)
            float A2 = ((r[0] + r[1]) + (r[2] + r[3])) + ((r[4] + r[5]) + (r[6] + r[7]));
            Aval = A1 + A2;
        }
        if (hb == 0) An[n0 + m] = Aval;
        double aS = (hb == 0) ? (double)Aval : 0.0;
#pragma unroll
        for (int s = 1; s < 32; s <<= 1) aS += __shfl_xor(aS, s, 64);
        aSred = aS;   // valid (32-row sum) on L==0; 0 on L==32
    }

    f32x16 acc[4];
#pragma unroll
    for (int nt = 0; nt < 4; ++nt)
#pragma unroll
        for (int r = 0; r < 16; ++r) acc[nt][r] = 0.f;

    float g1[16], g2[16]; int i1[16];
#pragma unroll
    for (int r = 0; r < 16; ++r) { g1[r] = -1e30f; g2[r] = -1e30f; i1[r] = 0; }

    __syncthreads();   // jt=0 staged (drain overlapped with preamble)

    for (int jt = 0; jt < 8; ++jt) {
        const int buf = jt & 1;
        // stage jt+1 BEFORE compute: latency hides under ds_read+MFMA phase.
        if (jt < 7) {
#pragma unroll
            for (int i = 0; i < 8; ++i)
                __builtin_amdgcn_global_load_lds(
                    (const AS1 void*)(gB4 + ((jt + 1) * 4096 + i * 512 + t)),
                    (AS3 void*)(&sB[buf ^ 1][i * 512 + wb]), 16, 0, 0);
        }

        // compute: 64 conflict-free ds_read_b128 + 64 MFMA (order == v3)
#pragma unroll
        for (int kc = 0; kc < 8; ++kc) {
#pragma unroll
            for (int kh = 0; kh < 2; ++kh) {
#pragma unroll
                for (int nt = 0; nt < 4; ++nt) {
                    half8 bh = *(const half8*)&sB[buf][((kc * 4 + nt) * 2 + kh) * 64 + L];
                    acc[nt] = __builtin_amdgcn_mfma_f32_32x32x16_f16(
                        Ah[kc * 2 + kh], bh, acc[nt], 0, 0, 0);
                }
            }
        }

        // fold acc -> top2 (max domain), reset acc
        float en512[4];
#pragma unroll
        for (int nt = 0; nt < 4; ++nt)
            en512[nt] = 512.0f * Bn[jt * 128 + nt * 32 + l5];
#pragma unroll
        for (int nt = 0; nt < 4; ++nt) {
            int jc = jt * 128 + nt * 32 + l5;
#pragma unroll
            for (int r = 0; r < 16; ++r) {
                float v = acc[nt][r] - en512[nt];
                g2[r] = fmaxf(g2[r], fminf(v, g1[r]));   // 2nd-largest
                bool gt = v > g1[r];                     // strict: first idx wins
                g1[r] = fmaxf(v, g1[r]);
                i1[r] = gt ? jc : i1[r];
                acc[nt][r] = 0.f;
            }
        }

        __syncthreads();   // buf[jt^1] fully staged; all waves done with buf
    }

    // cross-lane top2 merge over 32 lanes sharing rows (same hb)
    double lossP = 0.0;
#pragma unroll
    for (int r = 0; r < 16; ++r) {
        float v1 = g1[r], v2 = g2[r]; int ii = i1[r];
#pragma unroll
        for (int s = 1; s < 32; s <<= 1) {
            float o1 = __shfl_xor(v1, s, 64);
            int   oi = __shfl_xor(ii, s, 64);
            float o2 = __shfl_xor(v2, s, 64);
            float lo = fminf(v1, o1);
            if (o1 > v1 || (o1 == v1 && oi < ii)) { v1 = o1; ii = oi; }
            v2 = fmaxf(fmaxf(v2, o2), lo);
        }
        if (l5 == 0) {
            int rloc = rbase + 4 * hb + (r & 3) + 8 * (r >> 2);
            int n = n0 + rloc;
            idxw[n] = ii;
            out[IDX_OFF + n] = (float)ii;
            atomicAdd(&counts[ii], 1);
            lossP += -(double)v1 * (1.0 / 512.0);   // d_min = -g1/512
            if (v1 - v2 < GEPS) {
                int p = atomicAdd(&lcnt, 1);        // LDS atomic
                if (p < 256) lflag[p] = n;
            }
        }
    }
    if (l5 == 0) lsum[w * 2 + hb] = lossP + aSred;   // aSred=0 on hb=1 lane
    __syncthreads();
    if (t == 0) {
        double s = 0.0;
#pragma unroll
        for (int i = 0; i < 16; ++i) s += lsum[i];
        atomicAdd(loss_sum, s);
        lbase = lcnt ? atomicAdd(counter, lcnt) : 0;
    }
    __syncthreads();
    for (int i = t; i < lcnt; i += 512) {
        int p = lbase + i;
        if (p < 65536) list[p] = lflag[i];
    }
}

// ---------------------------------------------------------------------------
// K4: numpy-bit-faithful fp32 rescan of flagged rows + histogram delta-fix.
// thread t owns codes 4t..4t+3; e traversed via TRANSPOSED eT[c][j]:
// every wave load is 1KB contiguous. 8 rows/block.
// ---------------------------------------------------------------------------
__global__ __launch_bounds__(256, 2) void k_refine(
    const float* __restrict__ z, const float* __restrict__ eT,
    const float* __restrict__ Bn, const float* __restrict__ An,
    const int* __restrict__ counter, const int* __restrict__ list,
    int* __restrict__ idxw, float* __restrict__ out,
    int* __restrict__ counts)
{
    __shared__ float zs[8][256];
    __shared__ int   ns[8];
    __shared__ float ans[8];
    __shared__ float pv[4][8];
    __shared__ int   pi[4][8];
    int t = threadIdx.x;
    int cnt = min(*counter, 65536);
    for (int li0 = blockIdx.x * 8; li0 < cnt; li0 += gridDim.x * 8) {
        int nrows = min(8, cnt - li0);
        __syncthreads();
        if (t < 8) {
            int n = (t < nrows) ? list[li0 + t] : list[li0];
            ns[t] = n; ans[t] = An[n];
        }
        __syncthreads();
#pragma unroll
        for (int u = 0; u < 8; ++u) {
            int n = ns[u];
            zs[u][t] = z[(size_t)(n >> 12) * (EDIM * HW) + (n & 4095) + t * HW];
        }
        __syncthreads();

        // D[q][r]: dot(e[4t+q], zs[r]) accumulated in c-ascending fmaf order
        float D[4][8];
#pragma unroll
        for (int q = 0; q < 4; ++q)
#pragma unroll
            for (int r = 0; r < 8; ++r) D[q][r] = 0.f;

        for (int c4 = 0; c4 < 64; ++c4) {
            float4 ec[4];                       // codes 4t..4t+3 at c=4*c4+cc
#pragma unroll
            for (int cc = 0; cc < 4; ++cc)
                ec[cc] = *(const float4*)&eT[(size_t)(c4 * 4 + cc) * 1024 + 4 * t];
            float4 zr[8];                       // broadcast ds_read_b128
#pragma unroll
            for (int r = 0; r < 8; ++r)
                zr[r] = *(const float4*)&zs[r][c4 * 4];
#pragma unroll
            for (int cc = 0; cc < 4; ++cc) {
                const float* ep = (const float*)&ec[cc];
#pragma unroll
                for (int r = 0; r < 8; ++r) {
                    float zv = ((const float*)&zr[r])[cc];
                    D[0][r] = __builtin_fmaf(ep[0], zv, D[0][r]);
                    D[1][r] = __builtin_fmaf(ep[1], zv, D[1][r]);
                    D[2][r] = __builtin_fmaf(ep[2], zv, D[2][r]);
                    D[3][r] = __builtin_fmaf(ep[3], zv, D[3][r]);
                }
            }
        }

        float bm[8]; int bi[8];
#pragma unroll
        for (int r = 0; r < 8; ++r) { bm[r] = 1e30f; bi[r] = 1 << 30; }
        float4 bn4 = *(const float4*)&Bn[4 * t];
        {
#pragma clang fp contract(off)
#pragma unroll
            for (int q = 0; q < 4; ++q) {
                float bnj = ((const float*)&bn4)[q];
                int j = 4 * t + q;
#pragma unroll
                for (int r = 0; r < 8; ++r) {
                    float t2 = D[q][r] + D[q][r];
                    float s  = ans[r] + bnj;
                    float d  = s - t2;
                    if (d < bm[r]) { bm[r] = d; bi[r] = j; }   // ascending j: first wins
                }
            }
        }
        int wv = t >> 6, L = t & 63;
#pragma unroll
        for (int r = 0; r < 8; ++r) {
            float v = bm[r]; int ii = bi[r];
#pragma unroll
            for (int s = 1; s < 64; s <<= 1) {
                float ov = __shfl_xor(v, s, 64);
                int   oi = __shfl_xor(ii, s, 64);
                if (ov < v || (ov == v && oi < ii)) { v = ov; ii = oi; }
            }
            if (L == 0) { pv[wv][r] = v; pi[wv][r] = ii; }
        }
        __syncthreads();
        if (t < nrows) {
            float v = pv[0][t]; int ii = pi[0][t];
#pragma unroll
            for (int w2 = 1; w2 < 4; ++w2)
                if (pv[w2][t] < v || (pv[w2][t] == v && pi[w2][t] < ii)) { v = pv[w2][t]; ii = pi[w2][t]; }
            int n = ns[t];
            int old = idxw[n];
            if (old != ii) {
                idxw[n] = ii;
                out[IDX_OFF + n] = (float)ii;
                atomicSub(&counts[old], 1);
                atomicAdd(&counts[ii], 1);
            }
        }
    }
}

// ---------------------------------------------------------------------------
// K5: zq gather/scatter (loss via distance identity; idx final post-refine).
// ---------------------------------------------------------------------------
__global__ void k_gather(const float* __restrict__ e, const int* __restrict__ idxw,
                         float* __restrict__ out) {
    __shared__ int   jrow[256];
    __shared__ float Ls[8][260];
    int t = threadIdx.x;
    int rg = blockIdx.x >> 1, ch = blockIdx.x & 1;
    int n0 = rg * 256;
    int b = n0 >> 12, hw0 = n0 & 4095;
    jrow[t] = idxw[n0 + t];
    float* zqb = out + ZQ_OFF + (size_t)b * (EDIM * HW) + hw0 + (size_t)ch * 128 * HW;
    int w = t >> 6, L = t & 63;
    __syncthreads();

    for (int cc = 0; cc < 16; ++cc) {
        const float4* ep = (const float4*)(e + (size_t)jrow[t] * EDIM + ch * 128 + cc * 8);
        float4 v0 = ep[0], v1 = ep[1];
        Ls[0][t] = v0.x; Ls[1][t] = v0.y; Ls[2][t] = v0.z; Ls[3][t] = v0.w;
        Ls[4][t] = v1.x; Ls[5][t] = v1.y; Ls[6][t] = v1.z; Ls[7][t] = v1.w;
        __syncthreads();
#pragma unroll
        for (int i = 0; i < 2; ++i) {
            int c = w * 2 + i;
            float4 vv = *(const float4*)&Ls[c][L * 4];
            *(float4*)(zqb + (size_t)(cc * 8 + c) * HW + L * 4) = vv;
        }
        __syncthreads();
    }
}

// ---------------------------------------------------------------------------
// K6: finalize scalars
// ---------------------------------------------------------------------------
__global__ void k_final(const int* __restrict__ counts, const double* __restrict__ loss_sum,
                        float* __restrict__ out) {
    __shared__ float sred[4];
    int t = threadIdx.x;
    float s = 0.f;
    for (int qq = 0; qq < 4; ++qq) {
        float p = (float)counts[qq * 256 + t] * (1.0f / 65536.0f);
        s += p * logf(p + 1e-10f);
    }
#pragma unroll
    for (int sh = 1; sh < 64; sh <<= 1) s += __shfl_xor(s, sh, 64);
    if ((t & 63) == 0) sred[t >> 6] = s;
    __syncthreads();
    if (t == 0) {
        out[PERP_OFF] = expf(-(sred[0] + sred[1] + sred[2] + sred[3]));
        out[LOSS_OFF] = (float)(*loss_sum * 1.25 / 16777216.0);
    }
}

extern "C" void kernel_launch(void* const* d_in, const int* in_sizes, int n_in,
                              void* d_out, int out_size, void* d_ws, size_t ws_size,
                              hipStream_t stream) {
    const float* z = (const float*)d_in[0];
    const float* e = (const float*)d_in[1];
    float* out = (float*)d_out;
    char* ws = (char*)d_ws;

    _Float16* eh      = (_Float16*)(ws + WS_ESPH);
    float*    Bn      = (float*)(ws + WS_BNORM);
    int*      counts  = (int*)(ws + WS_COUNTS);
    int*      counter = (int*)(ws + WS_COUNTER);
    double*   loss_sum= (double*)(ws + WS_LOSS);
    float*    An      = (float*)(ws + WS_AN);
    int*      idxw    = (int*)(ws + WS_IDX);
    int*      list    = (int*)(ws + WS_LIST);
    float*    eT      = (float*)(ws + WS_ET);

    // zero counts + counter + loss accumulator (contiguous)
    hipMemsetAsync(ws + WS_COUNTS, 0, 4096 + 16 + 16, stream);

    k_prep_e   <<<1024, 256, 0, stream>>>(e, eh);
    k_transpose<<<32,   256, 0, stream>>>(e, eT);
    k_bnorm    <<<4,    256, 0, stream>>>(e, Bn);
    k_dist     <<<256,  512, 0, stream>>>(z, eh, Bn, idxw, out, counter, list, loss_sum, counts, An);
    k_refine   <<<2048, 256, 0, stream>>>(z, eT, Bn, An, counter, list, idxw, out, counts);
    k_gather   <<<512,  256, 0, stream>>>(e, idxw, out);
    k_final    <<<1,    256, 0, stream>>>(counts, loss_sum, out);
}

// Round 9
// 227.767 us; speedup vs baseline: 1.3038x; 1.0493x over previous
//
#include <hip/hip_runtime.h>

typedef _Float16 half8 __attribute__((ext_vector_type(8)));
typedef float f32x16 __attribute__((ext_vector_type(16)));

// Problem constants
#define EDIM 256
#define NE   1024
#define HW   4096

// d_out layout (fp32 elements): z_q[16777216], loss, perplexity, idx[65536]
#define ZQ_OFF   0
#define LOSS_OFF 16777216
#define PERP_OFF 16777217
#define IDX_OFF  16777218

// ws layout (byte offsets)
#define WS_ESPH    0                         // eh fragment-ordered f16, 512 KB
#define WS_BNORM   (1024*1024)               // 1024 f32
#define WS_COUNTS  (WS_BNORM + 4096)         // 1024 i32
#define WS_COUNTER (WS_COUNTS + 4096)        // i32 (+pad)
#define WS_LOSS    (WS_COUNTER + 16)         // double
#define WS_AN      (WS_LOSS + 16)            // 65536 f32
#define WS_IDX     (WS_AN + 65536*4)         // 65536 i32
#define WS_LIST    (WS_IDX + 65536*4)        // 65536 i32
#define WS_ET      (WS_LIST + 65536*4)       // eT[c][j] f32, 1 MB (16B aligned)

// refine margin in d-units; provable distortion bound ~1.9e-4 (single-term
// split residual 9.6e-5 + numpy fp32 rounding 9.2e-5). 1.6x safety.
#define EPS 3.0e-4f
// g = acc - 512*B_j tracked in max-domain; gap test g1-g2 < 512*EPS
#define GEPS (512.0f * EPS)

#define AS1 __attribute__((address_space(1)))
#define AS3 __attribute__((address_space(3)))

// ---------------------------------------------------------------------------
// K0: e*1024 -> f16 hi, FRAGMENT-ORDERED for 32x32x16 MFMA staging.
// ---------------------------------------------------------------------------
__global__ void k_prep_e(const float* __restrict__ e, _Float16* __restrict__ eh) {
    int t = blockIdx.x * 256 + threadIdx.x;   // 262144
    int j = t >> 8, c = t & 255;
    float v = e[t] * 1024.0f;                 // exact pow2 scale
    _Float16 h = (_Float16)v;
    int jt = j >> 7, nt = (j >> 5) & 3, lm = j & 31;
    int kc = c >> 5, r = c & 31, kh = r >> 4, hb = (r >> 3) & 1, kk = r & 7;
    int chunk = (((jt * 8 + kc) * 4 + nt) * 2 + kh) * 64 + hb * 32 + lm;
    eh[chunk * 8 + kk] = h;
}

// ---------------------------------------------------------------------------
// K0b: fp32 transpose e[j][c] -> eT[c][j] via LDS tile + FUSED Bn.
// 32 j-rows per block, 32 blocks. Bn replayed from the LDS tile with
// numpy's exact 8-accumulator chain (contract-off; mult-then-add; the
// 8-lane butterfly reproduces ((r0+r1)+(r2+r3))+((r4+r5)+(r6+r7))) ->
// bit-identical to the old k_bnorm, one fewer launch.
// ---------------------------------------------------------------------------
__global__ void k_transpose(const float* __restrict__ e, float* __restrict__ eT,
                            float* __restrict__ Bn) {
    __shared__ float tile[32][257];
    int b = blockIdx.x;            // j-tile [32b, 32b+32)
    int t = threadIdx.x;
#pragma unroll
    for (int i = 0; i < 32; ++i)
        tile[i][t] = e[(size_t)(32 * b + i) * 256 + t];
    __syncthreads();
    int jl = t & 31, cg = t >> 5;  // 8 c-groups of 32 lanes
#pragma unroll
    for (int k = 0; k < 32; ++k) {
        int c = cg * 32 + k;
        eT[(size_t)c * 1024 + 32 * b + jl] = tile[jl][c];
    }
    // fused Bn: 32 rows x 8 lanes; lane q owns accumulator r[q] (c == q mod 8)
    int row = t >> 3, q = t & 7;
    float A[2];
#pragma unroll
    for (int h = 0; h < 2; ++h) {
#pragma clang fp contract(off)
        float acc = 0.f;
        for (int i = 0; i < 16; ++i) {
            float v = tile[row][h * 128 + i * 8 + q];
            float sq = v * v;
            acc = (i == 0) ? sq : acc + sq;
        }
#pragma unroll
        for (int s = 1; s < 8; s <<= 1) acc += __shfl_xor(acc, s, 64);
        A[h] = acc;
    }
    if (q == 0) {
#pragma clang fp contract(off)
        Bn[32 * b + row] = A[0] + A[1];
    }
}

// ---------------------------------------------------------------------------
// K3 v7: MFMA distance + top-2 argmin + loss + histogram + fused rownorm
// + FUSED z_q gather tail.
// 256 blocks x 512 thr (8 waves x 32 rows), v3 staging (2x64 KB dbuf,
// bulk global_load_lds, one __syncthreads per jt).
// After the merge, per-block idx lives in LDS; the dead 128 KB sB is
// reused as transpose staging to write this block's 256 KB z_q slice
// (exact fp32 embedding gather). k_refine patches rows it changes.
// MFMA order identical to v3 -> bit-identical distances; An bit-identical.
// ---------------------------------------------------------------------------
__global__ __launch_bounds__(512, 2) void k_dist(
    const float* __restrict__ z, const _Float16* __restrict__ eh,
    const float* __restrict__ e, const float* __restrict__ Bn,
    int* __restrict__ idxw, float* __restrict__ out,
    int* __restrict__ counter, int* __restrict__ list,
    double* __restrict__ loss_sum, int* __restrict__ counts,
    float* __restrict__ An)
{
    __shared__ uint4  sB[2][4096];    // 2 x 64 KB (one jt-chunk each)
    __shared__ double lsum[16];
    __shared__ int    lflag[256];
    __shared__ int    idxs[256];
    __shared__ int    lcnt;
    __shared__ int    lbase;

    const int t  = threadIdx.x;       // 0..511
    const int w  = t >> 6;            // 8 waves
    const int L  = t & 63;
    const int l5 = L & 31;
    const int hb = L >> 5;
    const int n0 = blockIdx.x * 256;  // 256 blocks
    const int b  = n0 >> 12, hw0 = n0 & 4095;
    const float* zb = z + (size_t)b * (EDIM * HW) + hw0;
    const int rbase = w * 32;

    if (t == 0) lcnt = 0;

    const uint4* gB4 = (const uint4*)eh;
    const int wb = t & 448;           // w*64: wave-uniform lane-0 slot

    // stage(jt=0) into buf0 -- overlaps with the preamble below
#pragma unroll
    for (int i = 0; i < 8; ++i)
        __builtin_amdgcn_global_load_lds(
            (const AS1 void*)(gB4 + (i * 512 + t)),
            (AS3 void*)(&sB[0][i * 512 + wb]), 16, 0, 0);

    // Preamble: A fragments + fused numpy-exact rownorm (partner-lane shfl).
    half8 Ah[16];
    double aSred;
    {
        int m = rbase + l5;
        float r[8]; float A1 = 0.f, Aval;
#pragma unroll
        for (int ks = 0; ks < 16; ++ks) {
            float av[8], pv[8];
#pragma unroll
            for (int j = 0; j < 8; ++j)
                av[j] = zb[(ks * 16 + hb * 8 + j) * HW + m];
#pragma unroll
            for (int j = 0; j < 8; ++j)
                pv[j] = __shfl_xor(av[j], 32, 64);
            {
#pragma clang fp contract(off)
#pragma unroll
                for (int j = 0; j < 8; ++j) {
                    float a0 = hb ? pv[j] : av[j];   // first in c-order
                    float a1 = hb ? av[j] : pv[j];   // second in c-order
                    if ((ks & 7) == 0) r[j] = a0 * a0;
                    else               r[j] += a0 * a0;
                    r[j] += a1 * a1;
                }
            }
#pragma unroll
            for (int j = 0; j < 8; ++j)
                Ah[ks][j] = (_Float16)av[j];
            if (ks == 7) {
#pragma clang fp contract(off)
                A1 = ((r[0] + r[1]) + (r[2] + r[3])) + ((r[4] + r[5]) + (r[6] + r[7]));
            }
        }
        {
#pragma clang fp contract(off)
            float A2 = ((r[0] + r[1]) + (r[2] + r[3])) + ((r[4] + r[5]) + (r[6] + r[7]));
            Aval = A1 + A2;
        }
        if (hb == 0) An[n0 + m] = Aval;
        double aS = (hb == 0) ? (double)Aval : 0.0;
#pragma unroll
        for (int s = 1; s < 32; s <<= 1) aS += __shfl_xor(aS, s, 64);
        aSred = aS;   // valid (32-row sum) on L==0; 0 on L==32
    }

    f32x16 acc[4];
#pragma unroll
    for (int nt = 0; nt < 4; ++nt)
#pragma unroll
        for (int r = 0; r < 16; ++r) acc[nt][r] = 0.f;

    float g1[16], g2[16]; int i1[16];
#pragma unroll
    for (int r = 0; r < 16; ++r) { g1[r] = -1e30f; g2[r] = -1e30f; i1[r] = 0; }

    __syncthreads();   // jt=0 staged (drain overlapped with preamble)

    for (int jt = 0; jt < 8; ++jt) {
        const int buf = jt & 1;
        if (jt < 7) {
#pragma unroll
            for (int i = 0; i < 8; ++i)
                __builtin_amdgcn_global_load_lds(
                    (const AS1 void*)(gB4 + ((jt + 1) * 4096 + i * 512 + t)),
                    (AS3 void*)(&sB[buf ^ 1][i * 512 + wb]), 16, 0, 0);
        }

        // compute: 64 conflict-free ds_read_b128 + 64 MFMA (order == v3)
#pragma unroll
        for (int kc = 0; kc < 8; ++kc) {
#pragma unroll
            for (int kh = 0; kh < 2; ++kh) {
#pragma unroll
                for (int nt = 0; nt < 4; ++nt) {
                    half8 bh = *(const half8*)&sB[buf][((kc * 4 + nt) * 2 + kh) * 64 + L];
                    acc[nt] = __builtin_amdgcn_mfma_f32_32x32x16_f16(
                        Ah[kc * 2 + kh], bh, acc[nt], 0, 0, 0);
                }
            }
        }

        // fold acc -> top2 (max domain), reset acc
        float en512[4];
#pragma unroll
        for (int nt = 0; nt < 4; ++nt)
            en512[nt] = 512.0f * Bn[jt * 128 + nt * 32 + l5];
#pragma unroll
        for (int nt = 0; nt < 4; ++nt) {
            int jc = jt * 128 + nt * 32 + l5;
#pragma unroll
            for (int r = 0; r < 16; ++r) {
                float v = acc[nt][r] - en512[nt];
                g2[r] = fmaxf(g2[r], fminf(v, g1[r]));   // 2nd-largest
                bool gt = v > g1[r];                     // strict: first idx wins
                g1[r] = fmaxf(v, g1[r]);
                i1[r] = gt ? jc : i1[r];
                acc[nt][r] = 0.f;
            }
        }

        __syncthreads();   // buf[jt^1] fully staged; all waves done with buf
    }

    // cross-lane top2 merge over 32 lanes sharing rows (same hb)
    double lossP = 0.0;
#pragma unroll
    for (int r = 0; r < 16; ++r) {
        float v1 = g1[r], v2 = g2[r]; int ii = i1[r];
#pragma unroll
        for (int s = 1; s < 32; s <<= 1) {
            float o1 = __shfl_xor(v1, s, 64);
            int   oi = __shfl_xor(ii, s, 64);
            float o2 = __shfl_xor(v2, s, 64);
            float lo = fminf(v1, o1);
            if (o1 > v1 || (o1 == v1 && oi < ii)) { v1 = o1; ii = oi; }
            v2 = fmaxf(fmaxf(v2, o2), lo);
        }
        if (l5 == 0) {
            int rloc = rbase + 4 * hb + (r & 3) + 8 * (r >> 2);
            int n = n0 + rloc;
            idxw[n] = ii;
            idxs[rloc] = ii;
            out[IDX_OFF + n] = (float)ii;
            atomicAdd(&counts[ii], 1);
            lossP += -(double)v1 * (1.0 / 512.0);   // d_min = -g1/512
            if (v1 - v2 < GEPS) {
                int p = atomicAdd(&lcnt, 1);        // LDS atomic
                if (p < 256) lflag[p] = n;
            }
        }
    }
    if (l5 == 0) lsum[w * 2 + hb] = lossP + aSred;   // aSred=0 on hb=1 lane
    __syncthreads();
    if (t == 0) {
        double s = 0.0;
#pragma unroll
        for (int i = 0; i < 16; ++i) s += lsum[i];
        atomicAdd(loss_sum, s);
        lbase = lcnt ? atomicAdd(counter, lcnt) : 0;
    }
    __syncthreads();
    for (int i = t; i < lcnt; i += 512) {
        int p = lbase + i;
        if (p < 65536) list[p] = lflag[i];
    }

    // ---- fused z_q gather tail (reuses dead sB as [16][260] staging) ----
    {
        float* Ls = (float*)&sB[0][0];
        const int r_ = t & 255;           // row within block
        const int hf = t >> 8;            // c-half 0/1
        const int jc = idxs[r_];
        const float* er = e + (size_t)jc * EDIM + hf * 128;
        float* zqb = out + ZQ_OFF + (size_t)b * (EDIM * HW) + hw0;
        for (int cc = 0; cc < 16; ++cc) {
            float4 v0 = *(const float4*)(er + cc * 8);
            float4 v1 = *(const float4*)(er + cc * 8 + 4);
            __syncthreads();              // prev iter's Ls reads done
            Ls[(hf * 8 + 0) * 260 + r_] = v0.x;
            Ls[(hf * 8 + 1) * 260 + r_] = v0.y;
            Ls[(hf * 8 + 2) * 260 + r_] = v0.z;
            Ls[(hf * 8 + 3) * 260 + r_] = v0.w;
            Ls[(hf * 8 + 4) * 260 + r_] = v1.x;
            Ls[(hf * 8 + 5) * 260 + r_] = v1.y;
            Ls[(hf * 8 + 6) * 260 + r_] = v1.z;
            Ls[(hf * 8 + 7) * 260 + r_] = v1.w;
            __syncthreads();
#pragma unroll
            for (int i = 0; i < 2; ++i) {
                int cslot = w * 2 + i;                 // 0..15
                int c = (cslot >= 8 ? 128 : 0) + cc * 8 + (cslot & 7);
                float4 vv = *(const float4*)&Ls[cslot * 260 + L * 4];
                *(float4*)(zqb + (size_t)c * HW + L * 4) = vv;
            }
        }
    }
}

// ---------------------------------------------------------------------------
// K4: numpy-bit-faithful fp32 rescan of flagged rows + histogram delta-fix
// + z_q PATCH for changed rows (k_dist wrote provisional z_q).
// ---------------------------------------------------------------------------
__global__ __launch_bounds__(256, 2) void k_refine(
    const float* __restrict__ z, const float* __restrict__ eT,
    const float* __restrict__ e,
    const float* __restrict__ Bn, const float* __restrict__ An,
    const int* __restrict__ counter, const int* __restrict__ list,
    int* __restrict__ idxw, float* __restrict__ out,
    int* __restrict__ counts)
{
    __shared__ float zs[8][256];
    __shared__ int   ns[8];
    __shared__ float ans[8];
    __shared__ float pv[4][8];
    __shared__ int   pi[4][8];
    __shared__ int   chgN[8], chgJ[8];
    __shared__ int   nchg;
    int t = threadIdx.x;
    int cnt = min(*counter, 65536);
    for (int li0 = blockIdx.x * 8; li0 < cnt; li0 += gridDim.x * 8) {
        int nrows = min(8, cnt - li0);
        __syncthreads();
        if (t < 8) {
            int n = (t < nrows) ? list[li0 + t] : list[li0];
            ns[t] = n; ans[t] = An[n];
        }
        if (t == 255) nchg = 0;
        __syncthreads();
#pragma unroll
        for (int u = 0; u < 8; ++u) {
            int n = ns[u];
            zs[u][t] = z[(size_t)(n >> 12) * (EDIM * HW) + (n & 4095) + t * HW];
        }
        __syncthreads();

        // D[q][r]: dot(e[4t+q], zs[r]) accumulated in c-ascending fmaf order
        float D[4][8];
#pragma unroll
        for (int q = 0; q < 4; ++q)
#pragma unroll
            for (int r = 0; r < 8; ++r) D[q][r] = 0.f;

        for (int c4 = 0; c4 < 64; ++c4) {
            float4 ec[4];                       // codes 4t..4t+3 at c=4*c4+cc
#pragma unroll
            for (int cc = 0; cc < 4; ++cc)
                ec[cc] = *(const float4*)&eT[(size_t)(c4 * 4 + cc) * 1024 + 4 * t];
            float4 zr[8];                       // broadcast ds_read_b128
#pragma unroll
            for (int r = 0; r < 8; ++r)
                zr[r] = *(const float4*)&zs[r][c4 * 4];
#pragma unroll
            for (int cc = 0; cc < 4; ++cc) {
                const float* ep = (const float*)&ec[cc];
#pragma unroll
                for (int r = 0; r < 8; ++r) {
                    float zv = ((const float*)&zr[r])[cc];
                    D[0][r] = __builtin_fmaf(ep[0], zv, D[0][r]);
                    D[1][r] = __builtin_fmaf(ep[1], zv, D[1][r]);
                    D[2][r] = __builtin_fmaf(ep[2], zv, D[2][r]);
                    D[3][r] = __builtin_fmaf(ep[3], zv, D[3][r]);
                }
            }
        }

        float bm[8]; int bi[8];
#pragma unroll
        for (int r = 0; r < 8; ++r) { bm[r] = 1e30f; bi[r] = 1 << 30; }
        float4 bn4 = *(const float4*)&Bn[4 * t];
        {
#pragma clang fp contract(off)
#pragma unroll
            for (int q = 0; q < 4; ++q) {
                float bnj = ((const float*)&bn4)[q];
                int j = 4 * t + q;
#pragma unroll
                for (int r = 0; r < 8; ++r) {
                    float t2 = D[q][r] + D[q][r];
                    float s  = ans[r] + bnj;
                    float d  = s - t2;
                    if (d < bm[r]) { bm[r] = d; bi[r] = j; }   // ascending j: first wins
                }
            }
        }
        int wv = t >> 6, L = t & 63;
#pragma unroll
        for (int r = 0; r < 8; ++r) {
            float v = bm[r]; int ii = bi[r];
#pragma unroll
            for (int s = 1; s < 64; s <<= 1) {
                float ov = __shfl_xor(v, s, 64);
                int   oi = __shfl_xor(ii, s, 64);
                if (ov < v || (ov == v && oi < ii)) { v = ov; ii = oi; }
            }
            if (L == 0) { pv[wv][r] = v; pi[wv][r] = ii; }
        }
        __syncthreads();
        if (t < nrows) {
            float v = pv[0][t]; int ii = pi[0][t];
#pragma unroll
            for (int w2 = 1; w2 < 4; ++w2)
                if (pv[w2][t] < v || (pv[w2][t] == v && pi[w2][t] < ii)) { v = pv[w2][t]; ii = pi[w2][t]; }
            int n = ns[t];
            int old = idxw[n];
            if (old != ii) {
                idxw[n] = ii;
                out[IDX_OFF + n] = (float)ii;
                atomicSub(&counts[old], 1);
                atomicAdd(&counts[ii], 1);
                int p = atomicAdd(&nchg, 1);
                chgN[p] = n; chgJ[p] = ii;
            }
        }
        __syncthreads();
        // z_q patch: 256 threads write c=t for each changed row
        for (int u = 0; u < nchg; ++u) {
            int n = chgN[u], jj = chgJ[u];
            out[ZQ_OFF + (size_t)(n >> 12) * (EDIM * HW) + (size_t)t * HW + (n & 4095)]
                = e[jj * 256 + t];
        }
    }
}

// ---------------------------------------------------------------------------
// K6: finalize scalars
// ---------------------------------------------------------------------------
__global__ void k_final(const int* __restrict__ counts, const double* __restrict__ loss_sum,
                        float* __restrict__ out) {
    __shared__ float sred[4];
    int t = threadIdx.x;
    float s = 0.f;
    for (int qq = 0; qq < 4; ++qq) {
        float p = (float)counts[qq * 256 + t] * (1.0f / 65536.0f);
        s += p * logf(p + 1e-10f);
    }
#pragma unroll
    for (int sh = 1; sh < 64; sh <<= 1) s += __shfl_xor(s, sh, 64);
    if ((t & 63) == 0) sred[t >> 6] = s;
    __syncthreads();
    if (t == 0) {
        out[PERP_OFF] = expf(-(sred[0] + sred[1] + sred[2] + sred[3]));
        out[LOSS_OFF] = (float)(*loss_sum * 1.25 / 16777216.0);
    }
}

extern "C" void kernel_launch(void* const* d_in, const int* in_sizes, int n_in,
                              void* d_out, int out_size, void* d_ws, size_t ws_size,
                              hipStream_t stream) {
    const float* z = (const float*)d_in[0];
    const float* e = (const float*)d_in[1];
    float* out = (float*)d_out;
    char* ws = (char*)d_ws;

    _Float16* eh      = (_Float16*)(ws + WS_ESPH);
    float*    Bn      = (float*)(ws + WS_BNORM);
    int*      counts  = (int*)(ws + WS_COUNTS);
    int*      counter = (int*)(ws + WS_COUNTER);
    double*   loss_sum= (double*)(ws + WS_LOSS);
    float*    An      = (float*)(ws + WS_AN);
    int*      idxw    = (int*)(ws + WS_IDX);
    int*      list    = (int*)(ws + WS_LIST);
    float*    eT      = (float*)(ws + WS_ET);

    // zero counts + counter + loss accumulator (contiguous)
    hipMemsetAsync(ws + WS_COUNTS, 0, 4096 + 16 + 16, stream);

    k_prep_e   <<<1024, 256, 0, stream>>>(e, eh);
    k_transpose<<<32,   256, 0, stream>>>(e, eT, Bn);
    k_dist     <<<256,  512, 0, stream>>>(z, eh, e, Bn, idxw, out, counter, list, loss_sum, counts, An);
    k_refine   <<<2048, 256, 0, stream>>>(z, eT, e, Bn, An, counter, list, idxw, out, counts);
    k_final    <<<1,    256, 0, stream>>>(counts, loss_sum, out);
}